// Round 13
// baseline (339.269 us; speedup 1.0000x reference)
//
#include <hip/hip_runtime.h>

// VectorQuantizer: N=16384 rows, C=256, K=8192. inputs fp32, outputs fp32
// (z_q 4194304 ++ indices 16384 ++ loss 1).
// r22: 303us, absmax 0 (race fixed). kScr flat ~136us across 6 rounds of
// scheduling/conflict/reg attacks -- all at 12 waves/CU (64-row shape's
// acc[4][4]=64 AGPR + 84 VGPR = 148 regs forces (256,3)). The one clean
// untested lever: WAVE COUNT. r17's 32-row kScr = 84 VGPR + 32 AGPR = 116
// regs, fits the 128-reg cap of (256,4) -> 4 blocks/CU = 16 waves/CU
// (+33% latency hiding). r11's "occupancy null" was spill-confounded.
// r23 = r22 with kScr back to 32-row r17 geometry (acc[2][4], grid 2048,
// single queue/block -> kTailM mapping R*4+s == blk, no tail changes) +
// swizzled fragment-linear A-tile (8192 shorts, same D/off formulas, m<2)
// + launch_bounds(256,4). Every line from a passing kernel.
// Check: VGPR must read ~84-96 (64 => cap-squeeze; WRITE_SIZE jump =>
// spill => revert). If occupancy up but dur flat => shared-resource wall,
// structure at ceiling.
//
// margin_n = 2e-5*sqrt(A_n) + 4e-5; flag iff R~ + margin >= rowRunningMax
// (monotone LDS atomicMax, per 32-row x candSplit block; stale threshold
// only over-flags => safe). Exact path: F verbatim hs copy in LDS,
// sequential fmaf chain, u64 key tie-break -- byte-identical to r9-r22.
//
// Scratch in z_q float region of d_out (kZQ overwrites last); no d_ws.
// High-water 4,483,080 floats (= r14-r22's proven-safe envelope).

#define N_ROWS 16384
#define K_CAND 8192
#define CDIM   256
#define NELEM  4194304

#define SA_FLT   0          // A[16384] fp32 (numpy-pairwise-exact)
#define SK_FLT   16384      // keys u64[16384]
#define SL_FLT   49152      // lossAcc double
#define SQC_FLT  49160      // qcount u32[2048]
#define SBB_FLT  51208      // -B~ f32[8192]
#define SQ_FLT   59400      // queue u32[2048*624]
#define SFB_FLT  1337352    // fbf = bf16(2*f)[16384][256] as u16
#define SEB_FLT  3434504    // ebf2 = bf16(e) 16-cand panels (ends 4483080)
#define QCAP     624

typedef __attribute__((ext_vector_type(8))) short short8;
typedef __attribute__((ext_vector_type(4))) float f32x4;
typedef __attribute__((ext_vector_type(4))) unsigned uint32x4;

__device__ __forceinline__ unsigned short f2bf_rne(float x) {
    unsigned u = __float_as_uint(x);
    return (unsigned short)((u + 0x7fffu + ((u >> 16) & 1u)) >> 16);
}
__device__ __forceinline__ float bf2f(unsigned short u) {
    return __uint_as_float(((unsigned)u) << 16);
}
// monotone float->u32 map (handles negatives)
__device__ __forceinline__ unsigned ordU(float f) {
    unsigned u = __float_as_uint(f);
    return u ^ (((int)u >> 31) | 0x80000000u);
}

// ---- kAF: fused kA + kFbf (one hs pass) + keys/loss init -------------------
// grid 512 = 16 b x 32 yB; 32 rows x 256 c per block.
__global__ __launch_bounds__(256) void kAF(const float* __restrict__ hs,
                                           float* __restrict__ out) {
    float* A = out + SA_FLT;
    unsigned long long* keys = (unsigned long long*)(out + SK_FLT);
    unsigned short* fbf = (unsigned short*)(out + SFB_FLT);
    __shared__ float T[256][33];

    const int t = threadIdx.x, blk = blockIdx.x;
    const int b = blk >> 5, yB = blk & 31;
    const int row0 = b * 1024 + yB * 32;
    if (blk == 0 && t == 0) *(double*)(out + SL_FLT) = 0.0;
    if (t < 32) keys[row0 + t] = ~0ull;

    // stage 32 rows x 256 c fp32 VERBATIM (coalesced per 32-lane group)
    {
        int yl = t & 31, ch = t >> 5;     // ch 0..7
        const float* src = hs + ((size_t)b << 18) + yB * 32 + yl;
        #pragma unroll
        for (int i = 0; i < 32; ++i) {
            int c = i * 8 + ch;
            T[c][yl] = src[(size_t)c << 10];
        }
    }
    __syncthreads();

    // A-chain: wave 0 only; lane = yl + h*32. Ops identical to old kA:
    // per-h r[8] stripes, pairwise combine, then fadd(hsum0, hsum1).
    if (t < 64) {
        int yl = t & 31, h = t >> 5;
        float r[8];
        #pragma unroll
        for (int j = 0; j < 8; ++j) {
            float x = T[h * 128 + j][yl];
            r[j] = __fmul_rn(x, x);
        }
        for (int i = 8; i < 128; i += 8) {
            #pragma unroll
            for (int j = 0; j < 8; ++j) {
                float x = T[h * 128 + i + j][yl];
                r[j] = __fadd_rn(r[j], __fmul_rn(x, x));
            }
        }
        float hsum = __fadd_rn(
            __fadd_rn(__fadd_rn(r[0], r[1]), __fadd_rn(r[2], r[3])),
            __fadd_rn(__fadd_rn(r[4], r[5]), __fadd_rn(r[6], r[7])));
        float other = __shfl_down(hsum, 32);   // h=1 partner's hsum
        if (h == 0) A[row0 + yl] = __fadd_rn(hsum, other);
    }

    // fbf transpose: all threads; thread (yl, cq) emits 32 c of its row
    {
        int yl = t & 31, cq = t >> 5;
        unsigned short* dst = fbf + (((size_t)(row0 + yl)) << 8) + cq * 32;
        #pragma unroll
        for (int v = 0; v < 4; ++v) {
            short8 w;
            #pragma unroll
            for (int j = 0; j < 8; ++j)
                w[j] = (short)f2bf_rne(2.0f * T[cq * 32 + v * 8 + j][yl]);
            *(short8*)(dst + v * 8) = w;
        }
    }
}

// ---- kEbf: bf16(e) -> 16-cand panel layout + (-B~) -------------------------
// ebf2 layout (shorts): g=cand>>4, kc=c0/8 (0..31), cl=cand&15:
//   addr = g*4096 + kc*128 + cl*8   (panel 8KB, chunk row 256B, 16B/cand)
__global__ void kEbf(const float* __restrict__ emb, float* __restrict__ out) {
    unsigned short* ebf = (unsigned short*)(out + SEB_FLT);
    float* bbfNeg = out + SBB_FLT;
    int cand = blockIdx.x * 64 + threadIdx.x;     // grid 128 x 64
    const float* ep = emb + ((size_t)cand << 8);
    unsigned short* dp = ebf + (((size_t)(cand >> 4)) << 12) + (cand & 15) * 8;
    float s = 0.f;
    for (int c0 = 0; c0 < 256; c0 += 8) {
        short8 v;
        #pragma unroll
        for (int j = 0; j < 8; ++j) {
            unsigned short bb = f2bf_rne(ep[c0 + j]);
            v[j] = (short)bb;
            float eh = bf2f(bb);
            s = fmaf(eh, eh, s);
        }
        *(short8*)(dp + (c0 >> 3) * 128) = v;
    }
    bbfNeg[cand] = -s;
}

// ---- kScr: MFMA screen + flags -> per-block queue --------------------------
// r23: 32-row blocks, grid 2048 = 512 rowBlk x 4 candSplit, acc[2][4] =
// 32 AGPR + ~84 VGPR = fits (256,4) 128-reg cap -> 4 blocks/CU, 16 waves.
// Fragment-linear A-tile (8192 shorts) with XOR swizzle D^=(c32&7) both
// sides; reads stay contiguous-1KB permutation via off0/off1.
__global__ __launch_bounds__(256, 4) void kScr(const float* __restrict__ hs,
                                               const float* __restrict__ emb,
                                               float* __restrict__ out) {
    const float* A = out + SA_FLT;
    unsigned* qcount = (unsigned*)(out + SQC_FLT);
    const float* bbfNeg = out + SBB_FLT;
    unsigned* queue = (unsigned*)(out + SQ_FLT);
    const unsigned short* fbf = (const unsigned short*)(out + SFB_FLT);
    const unsigned short* ebf = (const unsigned short*)(out + SEB_FLT);

    __shared__ __align__(16) short As2[8192];     // fragment-linear A-tile
    __shared__ unsigned rowMaxOrd[32];
    __shared__ float margLds[32];
    __shared__ int lqn;

    const int t = threadIdx.x, blk = blockIdx.x;
    const int row0 = (blk >> 2) * 32;
    const int candSplit = (blk & 3) * 2048;
    const int lane = t & 63, wid = t >> 6;
    const int quad = lane >> 4, l15 = lane & 15;
    unsigned* qBlk = queue + (size_t)blk * QCAP;

    if (t < 32) {
        rowMaxOrd[t] = 0u;
        margLds[t] = 2.0e-5f * sqrtf(A[row0 + t]) + 4.0e-5f;
    }
    if (t == 0) lqn = 0;

    // stage A-tile ONCE, swizzled fragment-linear:
    // canonical chunk D = (r>>4)*512 + c32*16 + (r&15); store at D^(c32&7).
    {
        const unsigned short* src = fbf + ((size_t)row0 << 8);
        #pragma unroll
        for (int i = 0; i < 4; ++i) {
            int d = i * 256 + t;
            short8 v = *(const short8*)(src + d * 8);
            int r = d >> 5, c32 = d & 31;
            int D = ((r >> 4) << 9) + (c32 << 4) + (r & 15);
            D ^= (c32 & 7);
            *(short8*)&As2[D << 3] = v;
        }
    }
    __syncthreads();     // the ONLY barrier before the final qcount store

    // read-side swizzled offsets (shorts): even ks -> off0, odd ks -> off1
    const int off0 = ((quad << 4) + (l15 ^ quad)) << 3;
    const int off1 = ((quad << 4) + (l15 ^ quad ^ 4)) << 3;

    // loop-invariant margins -> registers (one batched LDS read per m)
    f32x4 mgv[2];
    #pragma unroll
    for (int m = 0; m < 2; ++m)
        mgv[m] = *(const f32x4*)&margLds[m * 16 + quad * 4];

    for (int cc = 0; cc < 8; ++cc) {
        const int candW = candSplit + cc * 256 + wid * 64;
        const unsigned short* ebW = ebf + (((size_t)candW) << 8)
                                       + quad * 128 + l15 * 8;
        float bneg[4];
        #pragma unroll
        for (int jc = 0; jc < 4; ++jc)
            bneg[jc] = bbfNeg[candW + jc * 16 + l15];

        f32x4 acc[2][4];
        #pragma unroll
        for (int jc = 0; jc < 4; ++jc)
            #pragma unroll
            for (int m = 0; m < 2; ++m)
                acc[m][jc] = (f32x4){0.f, 0.f, 0.f, 0.f};
        #pragma unroll
        for (int ks = 0; ks < 8; ++ks) {
            short8 bf[4];
            #pragma unroll
            for (int jc = 0; jc < 4; ++jc)
                bf[jc] = *(const short8*)(ebW + jc * 4096 + ks * 512);
            #pragma unroll
            for (int m = 0; m < 2; ++m) {
                short8 af = *(const short8*)&As2[((m * 8 + ks) << 9)
                                                 + ((ks & 1) ? off1 : off0)];
                #pragma unroll
                for (int jc = 0; jc < 4; ++jc)
                    acc[m][jc] = __builtin_amdgcn_mfma_f32_16x16x32_bf16(
                        af, bf[jc], acc[m][jc], 0, 0, 0);
            }
        }
        // flag: per-(m,reg) early-out; ballot consensus so the 16-lane
        // shuffle-max never runs with inactive lanes (garbage-max hazard).
        #pragma unroll
        for (int m = 0; m < 2; ++m) {
            uint32x4 thv = *(const uint32x4*)&rowMaxOrd[m * 16 + quad * 4];
            #pragma unroll
            for (int reg = 0; reg < 4; ++reg) {
                int rl = m * 16 + quad * 4 + reg;
                float x0 = __fadd_rn(acc[m][0][reg], bneg[0]);
                float x1 = __fadd_rn(acc[m][1][reg], bneg[1]);
                float x2 = __fadd_rn(acc[m][2][reg], bneg[2]);
                float x3 = __fadd_rn(acc[m][3][reg], bneg[3]);
                float vmax = fmaxf(fmaxf(x0, x1), fmaxf(x2, x3));
                unsigned th = thv[reg];
                float mg = mgv[m][reg];
                bool hot = ordU(__fadd_rn(vmax, mg)) >= th;
                unsigned long long bal = __ballot(hot);
                if (((bal >> (quad * 16)) & 0xFFFFull) == 0ull) continue;
                float g = vmax;                       // all 16 lanes active
                g = fmaxf(g, __shfl_xor(g, 1, 16));
                g = fmaxf(g, __shfl_xor(g, 2, 16));
                g = fmaxf(g, __shfl_xor(g, 4, 16));
                g = fmaxf(g, __shfl_xor(g, 8, 16));
                unsigned og = ordU(g);
                if (og > th) { atomicMax(&rowMaxOrd[rl], og); th = og; }
                float xs[4] = {x0, x1, x2, x3};
                #pragma unroll
                for (int jc = 0; jc < 4; ++jc) {
                    if (ordU(__fadd_rn(xs[jc], mg)) >= th) {
                        int slot = atomicAdd(&lqn, 1);
                        if (slot < QCAP)
                            qBlk[slot] = ((unsigned)rl << 13)
                                       | (unsigned)(candW + jc * 16 + l15);
                    }
                }
            }
        }
    }
    __syncthreads();
    if (t == 0) qcount[blk] = (unsigned)lqn;
}

// ---- kTailM: merged tail -- stage F once, drain 4 candSplit queues ---------
// grid 512 (one block per 32-row group). Queues at R*4+s (= kScr blk).
// Exact chain byte-identical to r9-r22.
__global__ __launch_bounds__(256, 4) void kTailM(const float* __restrict__ hs,
                                                 const float* __restrict__ emb,
                                                 float* __restrict__ out) {
    const float* A = out + SA_FLT;
    unsigned long long* keys = (unsigned long long*)(out + SK_FLT);
    const unsigned* qcount = (const unsigned*)(out + SQC_FLT);
    const unsigned* queue = (const unsigned*)(out + SQ_FLT);

    __shared__ __align__(16) float F[32][264];

    const int t = threadIdx.x, R = blockIdx.x;
    const int row0 = R * 32;

    int nq[4];
    #pragma unroll
    for (int s = 0; s < 4; ++s) nq[s] = (int)qcount[R * 4 + s];
    if ((nq[0] | nq[1] | nq[2] | nq[3]) == 0) return;

    // stage 32 rows fp32 VERBATIM into LDS (once, not 4x)
    {
        int yl = t & 31, cq = t >> 5;
        int nrow = row0 + yl;
        int b = nrow >> 10, yx = nrow & 1023;
        const float* src = hs + ((size_t)b << 18) + yx;
        #pragma unroll
        for (int i = 0; i < 32; ++i) {
            int c = i * 8 + cq;
            F[yl][c] = src[(size_t)c << 10];
        }
    }
    __syncthreads();

    for (int s = 0; s < 4; ++s) {
        int n = nq[s];
        if (n == 0) continue;
        if (n > QCAP) {                   // overflow: full scan of split s
            int cb = s * 2048;
            for (int p = t; p < 32 * 2048; p += 256) {
                int rl = p >> 11, cand = cb + (p & 2047);
                const float* ep = emb + ((size_t)cand << 8);
                float acc = 0.f;
                #pragma unroll 8
                for (int c0 = 0; c0 < 256; c0 += 4) {
                    f32x4 f4 = *(const f32x4*)&F[rl][c0];
                    f32x4 e4 = *(const f32x4*)(ep + c0);
                    acc = fmaf(f4[0], e4[0], acc);
                    acc = fmaf(f4[1], e4[1], acc);
                    acc = fmaf(f4[2], e4[2], acc);
                    acc = fmaf(f4[3], e4[3], acc);
                }
                int row = row0 + rl;
                float d = __fsub_rn(A[row], __fadd_rn(acc, acc));
                unsigned long long key =
                    ((unsigned long long)__float_as_uint(d) << 32) | (unsigned)cand;
                atomicMin(&keys[row], key);
            }
            continue;
        }
        const unsigned* qBlk = queue + (size_t)(R * 4 + s) * QCAP;
        for (int i = t; i < n; i += 256) {
            unsigned e = qBlk[i];
            int rl = (int)(e >> 13), cand = (int)(e & 8191u);
            const float* ep = emb + ((size_t)cand << 8);
            float acc = 0.f;
            #pragma unroll 8
            for (int c0 = 0; c0 < 256; c0 += 4) {
                f32x4 f4 = *(const f32x4*)&F[rl][c0];     // LDS, exact hs copy
                f32x4 e4 = *(const f32x4*)(ep + c0);      // global fp32 emb
                acc = fmaf(f4[0], e4[0], acc);
                acc = fmaf(f4[1], e4[1], acc);
                acc = fmaf(f4[2], e4[2], acc);
                acc = fmaf(f4[3], e4[3], acc);
            }
            int row = row0 + rl;
            float d = __fsub_rn(A[row], __fadd_rn(acc, acc));
            unsigned long long key =
                ((unsigned long long)__float_as_uint(d) << 32) | (unsigned)cand;
            atomicMin(&keys[row], key);
        }
    }
}

// ---- kPost: keys -> indices + loss partials (BEFORE any z_q write) ---------
__global__ void kPost(float* __restrict__ out) {
    const unsigned long long* keys = (const unsigned long long*)(out + SK_FLT);
    double* lossAcc = (double*)(out + SL_FLT);
    __shared__ double sd[256];
    int n = blockIdx.x * 256 + threadIdx.x;
    unsigned long long key = keys[n];
    unsigned idx = (unsigned)(key & 0xffffffffu) & 8191u;
    float d = __uint_as_float((unsigned)(key >> 32));
    out[NELEM + n] = (float)idx;
    sd[threadIdx.x] = (double)d;
    __syncthreads();
    for (int s = 128; s > 0; s >>= 1) {
        if (threadIdx.x < s) sd[threadIdx.x] += sd[threadIdx.x + s];
        __syncthreads();
    }
    if (threadIdx.x == 0) atomicAdd(lossAcc, sd[0]);
}

__global__ void kLoss(float* __restrict__ out) {
    if (threadIdx.x == 0) {
        double loss = 1.25 * (*(const double*)(out + SL_FLT)) / (double)NELEM;
        out[NELEM + N_ROWS] = (float)loss;
    }
}

// ---- kZQ: 64n x 64c LDS-tiled gather (reads indices from output region) ----
// grid 1024 = 256 nTile x 4 cTile. idx from out[NELEM+n] (stable, outside
// z_q region). Per-element formula byte-identical: out = fadd(h, fsub(e,h)).
__global__ __launch_bounds__(256) void kZQ(const float* __restrict__ hs,
                                           const float* __restrict__ emb,
                                           float* __restrict__ out) {
    __shared__ float E[64][65];           // [local c][local n]
    __shared__ unsigned idxL[64];

    const int t = threadIdx.x, blk = blockIdx.x;
    const int nt = blk >> 2, ct = blk & 3;
    const int row0 = nt * 64, c0 = ct * 64;
    const int b = row0 >> 10, yx0 = row0 & 1023;

    if (t < 64) idxL[t] = (unsigned)out[NELEM + row0 + t] & 8191u;
    __syncthreads();

    // gather: 4 threads/row, each reads 16 consecutive c (64B) -> LDS scatter
    {
        int r = t >> 2, j = t & 3;
        const float* ep = emb + ((size_t)idxL[r] << 8) + c0 + j * 16;
        #pragma unroll
        for (int q = 0; q < 4; ++q) {
            f32x4 v = *(const f32x4*)(ep + q * 4);
            #pragma unroll
            for (int i = 0; i < 4; ++i)
                E[j * 16 + q * 4 + i][r] = v[i];
        }
    }
    __syncthreads();

    // emit: thread (yl, ch): 16 c each; h read / z_q write coalesced
    {
        int yl = t & 63, ch = t >> 6;
        #pragma unroll
        for (int i = 0; i < 16; ++i) {
            int cl = ch * 16 + i;
            size_t o = ((size_t)b << 18) | ((size_t)(c0 + cl) << 10)
                     | (size_t)(yx0 + yl);
            float h = hs[o];
            float e = E[cl][yl];
            out[o] = __fadd_rn(h, __fsub_rn(e, h));
        }
    }
}

extern "C" void kernel_launch(void* const* d_in, const int* in_sizes, int n_in,
                              void* d_out, int out_size, void* d_ws, size_t ws_size,
                              hipStream_t stream) {
    const float* hs  = (const float*)d_in[0];
    const float* emb = (const float*)d_in[1];
    float* out = (float*)d_out;

    kAF<<<512, 256, 0, stream>>>(hs, out);
    kEbf<<<K_CAND / 64, 64, 0, stream>>>(emb, out);
    kScr<<<2048, 256, 0, stream>>>(hs, emb, out);
    kTailM<<<512, 256, 0, stream>>>(hs, emb, out);
    kPost<<<N_ROWS / 256, 256, 0, stream>>>(out);
    kLoss<<<1, 64, 0, stream>>>(out);
    kZQ<<<1024, 256, 0, stream>>>(hs, emb, out);
}

// Round 14
// 303.262 us; speedup vs baseline: 1.1187x; 1.1187x over previous
//
#include <hip/hip_runtime.h>

// VectorQuantizer: N=16384 rows, C=256, K=8192. inputs fp32, outputs fp32
// (z_q 4194304 ++ indices 16384 ++ loss 1).
// r23 (32-row kScr @ (256,4) for 16 waves/CU) REVERTED by decision rule:
// VGPR_Count=64 (cap squeeze) + WRITE_SIZE 3.4->43.9MB (spills) -> kScr
// 136->170us. Occupancy question answered: spill-free 12-wave = 136us,
// spilled 16-wave = 170us; stall is structural at this MFMA shape.
// r24 = r22 restored (best valid 303us) + kAF/kEbf merged into one launch
// (kAFE grid 544: blocks 0-511 = kAF body, 512-543 = kEbf body at 256
// threads; block-uniform branch, disjoint in/out, bodies byte-identical).
//
// margin_n = 2e-5*sqrt(A_n) + 4e-5; flag iff R~ + margin >= rowRunningMax
// (monotone LDS atomicMax, per 64-row x candSplit block; stale threshold
// only over-flags => safe). Exact path: F verbatim hs copy in LDS,
// sequential fmaf chain, u64 key tie-break -- byte-identical to r9-r22.
//
// Scratch in z_q float region of d_out (kZQ overwrites last); no d_ws.
// High-water 4,483,080 floats (= r14-r22's proven-safe envelope).

#define N_ROWS 16384
#define K_CAND 8192
#define CDIM   256
#define NELEM  4194304

#define SA_FLT   0          // A[16384] fp32 (numpy-pairwise-exact)
#define SK_FLT   16384      // keys u64[16384]
#define SL_FLT   49152      // lossAcc double
#define SQC_FLT  49160      // qcount u32[2048]
#define SBB_FLT  51208      // -B~ f32[8192]
#define SQ_FLT   59400      // queue u32[2048*624]
#define SFB_FLT  1337352    // fbf = bf16(2*f)[16384][256] as u16
#define SEB_FLT  3434504    // ebf2 = bf16(e) 16-cand panels (ends 4483080)
#define QCAP     624

typedef __attribute__((ext_vector_type(8))) short short8;
typedef __attribute__((ext_vector_type(4))) float f32x4;
typedef __attribute__((ext_vector_type(4))) unsigned uint32x4;

__device__ __forceinline__ unsigned short f2bf_rne(float x) {
    unsigned u = __float_as_uint(x);
    return (unsigned short)((u + 0x7fffu + ((u >> 16) & 1u)) >> 16);
}
__device__ __forceinline__ float bf2f(unsigned short u) {
    return __uint_as_float(((unsigned)u) << 16);
}
// monotone float->u32 map (handles negatives)
__device__ __forceinline__ unsigned ordU(float f) {
    unsigned u = __float_as_uint(f);
    return u ^ (((int)u >> 31) | 0x80000000u);
}

// ---- kAFE: fused kA + kFbf (blocks 0..511) ++ kEbf (blocks 512..543) -------
// kAF part: grid 512 = 16 b x 32 yB; 32 rows x 256 c per block.
// kEbf part: 32 blocks x 256 threads; panel layout g*4096 + kc*128 + cl*8.
__global__ __launch_bounds__(256) void kAFE(const float* __restrict__ hs,
                                            const float* __restrict__ emb,
                                            float* __restrict__ out) {
    const int t = threadIdx.x, blk = blockIdx.x;

    if (blk >= 512) {                     // ---- kEbf body (byte-identical)
        unsigned short* ebf = (unsigned short*)(out + SEB_FLT);
        float* bbfNeg = out + SBB_FLT;
        int cand = (blk - 512) * 256 + t;
        const float* ep = emb + ((size_t)cand << 8);
        unsigned short* dp = ebf + (((size_t)(cand >> 4)) << 12) + (cand & 15) * 8;
        float s = 0.f;
        for (int c0 = 0; c0 < 256; c0 += 8) {
            short8 v;
            #pragma unroll
            for (int j = 0; j < 8; ++j) {
                unsigned short bb = f2bf_rne(ep[c0 + j]);
                v[j] = (short)bb;
                float eh = bf2f(bb);
                s = fmaf(eh, eh, s);
            }
            *(short8*)(dp + (c0 >> 3) * 128) = v;
        }
        bbfNeg[cand] = -s;
        return;
    }

    // ---- kAF body (byte-identical to r22)
    float* A = out + SA_FLT;
    unsigned long long* keys = (unsigned long long*)(out + SK_FLT);
    unsigned short* fbf = (unsigned short*)(out + SFB_FLT);
    __shared__ float T[256][33];

    const int b = blk >> 5, yB = blk & 31;
    const int row0 = b * 1024 + yB * 32;
    if (blk == 0 && t == 0) *(double*)(out + SL_FLT) = 0.0;
    if (t < 32) keys[row0 + t] = ~0ull;

    // stage 32 rows x 256 c fp32 VERBATIM (coalesced per 32-lane group)
    {
        int yl = t & 31, ch = t >> 5;     // ch 0..7
        const float* src = hs + ((size_t)b << 18) + yB * 32 + yl;
        #pragma unroll
        for (int i = 0; i < 32; ++i) {
            int c = i * 8 + ch;
            T[c][yl] = src[(size_t)c << 10];
        }
    }
    __syncthreads();

    // A-chain: wave 0 only; lane = yl + h*32. Ops identical to old kA:
    // per-h r[8] stripes, pairwise combine, then fadd(hsum0, hsum1).
    if (t < 64) {
        int yl = t & 31, h = t >> 5;
        float r[8];
        #pragma unroll
        for (int j = 0; j < 8; ++j) {
            float x = T[h * 128 + j][yl];
            r[j] = __fmul_rn(x, x);
        }
        for (int i = 8; i < 128; i += 8) {
            #pragma unroll
            for (int j = 0; j < 8; ++j) {
                float x = T[h * 128 + i + j][yl];
                r[j] = __fadd_rn(r[j], __fmul_rn(x, x));
            }
        }
        float hsum = __fadd_rn(
            __fadd_rn(__fadd_rn(r[0], r[1]), __fadd_rn(r[2], r[3])),
            __fadd_rn(__fadd_rn(r[4], r[5]), __fadd_rn(r[6], r[7])));
        float other = __shfl_down(hsum, 32);   // h=1 partner's hsum
        if (h == 0) A[row0 + yl] = __fadd_rn(hsum, other);
    }

    // fbf transpose: all threads; thread (yl, cq) emits 32 c of its row
    {
        int yl = t & 31, cq = t >> 5;
        unsigned short* dst = fbf + (((size_t)(row0 + yl)) << 8) + cq * 32;
        #pragma unroll
        for (int v = 0; v < 4; ++v) {
            short8 w;
            #pragma unroll
            for (int j = 0; j < 8; ++j)
                w[j] = (short)f2bf_rne(2.0f * T[cq * 32 + v * 8 + j][yl]);
            *(short8*)(dst + v * 8) = w;
        }
    }
}

// ---- kScr: MFMA screen + flags -> per-half queues (r22 verbatim) -----------
// grid 1024 = 256 rowBlk x 4 candSplit. acc[4][4] = 64 AGPR; cap 170.
// Fragment-linear A-tile with XOR swizzle D^=(c32&7) on BOTH sides:
// writes spread 32->4-way; reads remain a contiguous-1KB permutation
// (conflict-free) selected via precomputed off0/off1 (zero loop VALU).
__global__ __launch_bounds__(256, 3) void kScr(const float* __restrict__ hs,
                                               const float* __restrict__ emb,
                                               float* __restrict__ out) {
    const float* A = out + SA_FLT;
    unsigned* qcount = (unsigned*)(out + SQC_FLT);
    const float* bbfNeg = out + SBB_FLT;
    unsigned* queue = (unsigned*)(out + SQ_FLT);
    const unsigned short* fbf = (const unsigned short*)(out + SFB_FLT);
    const unsigned short* ebf = (const unsigned short*)(out + SEB_FLT);

    __shared__ __align__(16) short As2[16384];    // fragment-linear A-tile
    __shared__ unsigned rowMaxOrd[64];
    __shared__ float margLds[64];
    __shared__ int lqnH[2];

    const int t = threadIdx.x, blk = blockIdx.x;
    const int row0 = (blk >> 2) * 64;
    const int candSplit = (blk & 3) * 2048;
    const int lane = t & 63, wid = t >> 6;
    const int quad = lane >> 4, l15 = lane & 15;
    const int qb0 = (blk >> 2) * 8 + (blk & 3);
    unsigned* qB[2] = { queue + (size_t)qb0 * QCAP,
                        queue + (size_t)(qb0 + 4) * QCAP };

    if (t < 64) {
        rowMaxOrd[t] = 0u;
        margLds[t] = 2.0e-5f * sqrtf(A[row0 + t]) + 4.0e-5f;
    }
    if (t < 2) lqnH[t] = 0;

    // stage A-tile ONCE, swizzled fragment-linear:
    // canonical chunk D = (r>>4)*512 + c32*16 + (r&15); store at D^(c32&7).
    {
        const unsigned short* src = fbf + ((size_t)row0 << 8);
        #pragma unroll
        for (int i = 0; i < 8; ++i) {
            int d = i * 256 + t;
            short8 v = *(const short8*)(src + d * 8);
            int r = d >> 5, c32 = d & 31;
            int D = ((r >> 4) << 9) + (c32 << 4) + (r & 15);
            D ^= (c32 & 7);
            *(short8*)&As2[D << 3] = v;
        }
    }
    __syncthreads();     // the ONLY barrier before the final qcount store

    // read-side swizzled offsets (shorts): even ks -> off0, odd ks -> off1
    const int off0 = ((quad << 4) + (l15 ^ quad)) << 3;
    const int off1 = ((quad << 4) + (l15 ^ quad ^ 4)) << 3;

    // loop-invariant margins -> registers (one batched LDS read per m)
    f32x4 mgv[4];
    #pragma unroll
    for (int m = 0; m < 4; ++m)
        mgv[m] = *(const f32x4*)&margLds[m * 16 + quad * 4];

    for (int cc = 0; cc < 8; ++cc) {
        const int candW = candSplit + cc * 256 + wid * 64;
        const unsigned short* ebW = ebf + (((size_t)candW) << 8)
                                       + quad * 128 + l15 * 8;
        float bneg[4];
        #pragma unroll
        for (int jc = 0; jc < 4; ++jc)
            bneg[jc] = bbfNeg[candW + jc * 16 + l15];

        f32x4 acc[4][4];
        #pragma unroll
        for (int jc = 0; jc < 4; ++jc)
            #pragma unroll
            for (int m = 0; m < 4; ++m)
                acc[m][jc] = (f32x4){0.f, 0.f, 0.f, 0.f};
        #pragma unroll
        for (int ks = 0; ks < 8; ++ks) {
            short8 bf[4];
            #pragma unroll
            for (int jc = 0; jc < 4; ++jc)
                bf[jc] = *(const short8*)(ebW + jc * 4096 + ks * 512);
            #pragma unroll
            for (int m = 0; m < 4; ++m) {
                short8 af = *(const short8*)&As2[((m * 8 + ks) << 9)
                                                 + ((ks & 1) ? off1 : off0)];
                #pragma unroll
                for (int jc = 0; jc < 4; ++jc)
                    acc[m][jc] = __builtin_amdgcn_mfma_f32_16x16x32_bf16(
                        af, bf[jc], acc[m][jc], 0, 0, 0);
            }
        }
        // flag: per-(m,reg) early-out; ballot consensus so the 16-lane
        // shuffle-max never runs with inactive lanes (garbage-max hazard).
        #pragma unroll
        for (int m = 0; m < 4; ++m) {
            uint32x4 thv = *(const uint32x4*)&rowMaxOrd[m * 16 + quad * 4];
            #pragma unroll
            for (int reg = 0; reg < 4; ++reg) {
                int rl = m * 16 + quad * 4 + reg;
                float x0 = __fadd_rn(acc[m][0][reg], bneg[0]);
                float x1 = __fadd_rn(acc[m][1][reg], bneg[1]);
                float x2 = __fadd_rn(acc[m][2][reg], bneg[2]);
                float x3 = __fadd_rn(acc[m][3][reg], bneg[3]);
                float vmax = fmaxf(fmaxf(x0, x1), fmaxf(x2, x3));
                unsigned th = thv[reg];
                float mg = mgv[m][reg];
                bool hot = ordU(__fadd_rn(vmax, mg)) >= th;
                unsigned long long bal = __ballot(hot);
                if (((bal >> (quad * 16)) & 0xFFFFull) == 0ull) continue;
                float g = vmax;                       // all 16 lanes active
                g = fmaxf(g, __shfl_xor(g, 1, 16));
                g = fmaxf(g, __shfl_xor(g, 2, 16));
                g = fmaxf(g, __shfl_xor(g, 4, 16));
                g = fmaxf(g, __shfl_xor(g, 8, 16));
                unsigned og = ordU(g);
                if (og > th) { atomicMax(&rowMaxOrd[rl], og); th = og; }
                float xs[4] = {x0, x1, x2, x3};
                #pragma unroll
                for (int jc = 0; jc < 4; ++jc) {
                    if (ordU(__fadd_rn(xs[jc], mg)) >= th) {
                        int slot = atomicAdd(&lqnH[m >> 1], 1);
                        if (slot < QCAP)
                            qB[m >> 1][slot] = ((unsigned)(rl & 31) << 13)
                                             | (unsigned)(candW + jc * 16 + l15);
                    }
                }
            }
        }
    }
    __syncthreads();
    if (t < 2) qcount[qb0 + t * 4] = (unsigned)lqnH[t];
}

// ---- kTailM: merged tail -- stage F once, drain 4 candSplit queues ---------
// grid 512 (one block per 32-row group). Queues at R*4+s. Exact chain
// byte-identical to r9-r22.
__global__ __launch_bounds__(256, 4) void kTailM(const float* __restrict__ hs,
                                                 const float* __restrict__ emb,
                                                 float* __restrict__ out) {
    const float* A = out + SA_FLT;
    unsigned long long* keys = (unsigned long long*)(out + SK_FLT);
    const unsigned* qcount = (const unsigned*)(out + SQC_FLT);
    const unsigned* queue = (const unsigned*)(out + SQ_FLT);

    __shared__ __align__(16) float F[32][264];

    const int t = threadIdx.x, R = blockIdx.x;
    const int row0 = R * 32;

    int nq[4];
    #pragma unroll
    for (int s = 0; s < 4; ++s) nq[s] = (int)qcount[R * 4 + s];
    if ((nq[0] | nq[1] | nq[2] | nq[3]) == 0) return;

    // stage 32 rows fp32 VERBATIM into LDS (once, not 4x)
    {
        int yl = t & 31, cq = t >> 5;
        int nrow = row0 + yl;
        int b = nrow >> 10, yx = nrow & 1023;
        const float* src = hs + ((size_t)b << 18) + yx;
        #pragma unroll
        for (int i = 0; i < 32; ++i) {
            int c = i * 8 + cq;
            F[yl][c] = src[(size_t)c << 10];
        }
    }
    __syncthreads();

    for (int s = 0; s < 4; ++s) {
        int n = nq[s];
        if (n == 0) continue;
        if (n > QCAP) {                   // overflow: full scan of split s
            int cb = s * 2048;
            for (int p = t; p < 32 * 2048; p += 256) {
                int rl = p >> 11, cand = cb + (p & 2047);
                const float* ep = emb + ((size_t)cand << 8);
                float acc = 0.f;
                #pragma unroll 8
                for (int c0 = 0; c0 < 256; c0 += 4) {
                    f32x4 f4 = *(const f32x4*)&F[rl][c0];
                    f32x4 e4 = *(const f32x4*)(ep + c0);
                    acc = fmaf(f4[0], e4[0], acc);
                    acc = fmaf(f4[1], e4[1], acc);
                    acc = fmaf(f4[2], e4[2], acc);
                    acc = fmaf(f4[3], e4[3], acc);
                }
                int row = row0 + rl;
                float d = __fsub_rn(A[row], __fadd_rn(acc, acc));
                unsigned long long key =
                    ((unsigned long long)__float_as_uint(d) << 32) | (unsigned)cand;
                atomicMin(&keys[row], key);
            }
            continue;
        }
        const unsigned* qBlk = queue + (size_t)(R * 4 + s) * QCAP;
        for (int i = t; i < n; i += 256) {
            unsigned e = qBlk[i];
            int rl = (int)(e >> 13), cand = (int)(e & 8191u);
            const float* ep = emb + ((size_t)cand << 8);
            float acc = 0.f;
            #pragma unroll 8
            for (int c0 = 0; c0 < 256; c0 += 4) {
                f32x4 f4 = *(const f32x4*)&F[rl][c0];     // LDS, exact hs copy
                f32x4 e4 = *(const f32x4*)(ep + c0);      // global fp32 emb
                acc = fmaf(f4[0], e4[0], acc);
                acc = fmaf(f4[1], e4[1], acc);
                acc = fmaf(f4[2], e4[2], acc);
                acc = fmaf(f4[3], e4[3], acc);
            }
            int row = row0 + rl;
            float d = __fsub_rn(A[row], __fadd_rn(acc, acc));
            unsigned long long key =
                ((unsigned long long)__float_as_uint(d) << 32) | (unsigned)cand;
            atomicMin(&keys[row], key);
        }
    }
}

// ---- kPost: keys -> indices + loss partials (BEFORE any z_q write) ---------
__global__ void kPost(float* __restrict__ out) {
    const unsigned long long* keys = (const unsigned long long*)(out + SK_FLT);
    double* lossAcc = (double*)(out + SL_FLT);
    __shared__ double sd[256];
    int n = blockIdx.x * 256 + threadIdx.x;
    unsigned long long key = keys[n];
    unsigned idx = (unsigned)(key & 0xffffffffu) & 8191u;
    float d = __uint_as_float((unsigned)(key >> 32));
    out[NELEM + n] = (float)idx;
    sd[threadIdx.x] = (double)d;
    __syncthreads();
    for (int s = 128; s > 0; s >>= 1) {
        if (threadIdx.x < s) sd[threadIdx.x] += sd[threadIdx.x + s];
        __syncthreads();
    }
    if (threadIdx.x == 0) atomicAdd(lossAcc, sd[0]);
}

__global__ void kLoss(float* __restrict__ out) {
    if (threadIdx.x == 0) {
        double loss = 1.25 * (*(const double*)(out + SL_FLT)) / (double)NELEM;
        out[NELEM + N_ROWS] = (float)loss;
    }
}

// ---- kZQ: 64n x 64c LDS-tiled gather (reads indices from output region) ----
// grid 1024 = 256 nTile x 4 cTile. idx from out[NELEM+n] (stable, outside
// z_q region). Per-element formula byte-identical: out = fadd(h, fsub(e,h)).
__global__ __launch_bounds__(256) void kZQ(const float* __restrict__ hs,
                                           const float* __restrict__ emb,
                                           float* __restrict__ out) {
    __shared__ float E[64][65];           // [local c][local n]
    __shared__ unsigned idxL[64];

    const int t = threadIdx.x, blk = blockIdx.x;
    const int nt = blk >> 2, ct = blk & 3;
    const int row0 = nt * 64, c0 = ct * 64;
    const int b = row0 >> 10, yx0 = row0 & 1023;

    if (t < 64) idxL[t] = (unsigned)out[NELEM + row0 + t] & 8191u;
    __syncthreads();

    // gather: 4 threads/row, each reads 16 consecutive c (64B) -> LDS scatter
    {
        int r = t >> 2, j = t & 3;
        const float* ep = emb + ((size_t)idxL[r] << 8) + c0 + j * 16;
        #pragma unroll
        for (int q = 0; q < 4; ++q) {
            f32x4 v = *(const f32x4*)(ep + q * 4);
            #pragma unroll
            for (int i = 0; i < 4; ++i)
                E[j * 16 + q * 4 + i][r] = v[i];
        }
    }
    __syncthreads();

    // emit: thread (yl, ch): 16 c each; h read / z_q write coalesced
    {
        int yl = t & 63, ch = t >> 6;
        #pragma unroll
        for (int i = 0; i < 16; ++i) {
            int cl = ch * 16 + i;
            size_t o = ((size_t)b << 18) | ((size_t)(c0 + cl) << 10)
                     | (size_t)(yx0 + yl);
            float h = hs[o];
            float e = E[cl][yl];
            out[o] = __fadd_rn(h, __fsub_rn(e, h));
        }
    }
}

extern "C" void kernel_launch(void* const* d_in, const int* in_sizes, int n_in,
                              void* d_out, int out_size, void* d_ws, size_t ws_size,
                              hipStream_t stream) {
    const float* hs  = (const float*)d_in[0];
    const float* emb = (const float*)d_in[1];
    float* out = (float*)d_out;

    kAFE<<<544, 256, 0, stream>>>(hs, emb, out);
    kScr<<<1024, 256, 0, stream>>>(hs, emb, out);
    kTailM<<<512, 256, 0, stream>>>(hs, emb, out);
    kPost<<<N_ROWS / 256, 256, 0, stream>>>(out);
    kLoss<<<1, 64, 0, stream>>>(out);
    kZQ<<<1024, 256, 0, stream>>>(hs, emb, out);
}

// Round 15
// 301.314 us; speedup vs baseline: 1.1260x; 1.0065x over previous
//
#include <hip/hip_runtime.h>

// VectorQuantizer: N=16384 rows, C=256, K=8192. inputs fp32, outputs fp32
// (z_q 4194304 ++ indices 16384 ++ loss 1).
// r24: r22 restored (303us, absmax 0); kAF+kEbf merge saved 0.0us ->
// launch gaps are NOT the aux cost. kScr steady at 136.8 (VGPR 84, no
// spill). Last untested kScr mechanism: flag-phase queue stores (into out)
// may-alias ebf (also in out), so the compiler CANNOT hoist next cc's
// ks=0 B-frag loads above them -> each cc opens with ~200-400cyc exposed
// L2 latency, 8x/wave.
// r25: explicit cross-flag-phase prefetch: load next cc's ks=0 frags
// (bf0[4], +16 VGPR, 84+16=100 <= 106 budget at (256,3)) AFTER the MFMA
// block, BEFORE the flag phase -- program order pins the loads above the
// may-alias stores; the ~2000cyc flag VALU hides the L2 latency. MFMA
// accumulation order per acc unchanged (ks ascending, same addresses) =>
// bit-identical. cc=7 prefetches its own ks=0 (discarded, in-bounds).
// Checks: VGPR ~96-106 (84 = sank, null); WRITE_SIZE ~3.4MB (jump=spill).
//
// margin_n = 2e-5*sqrt(A_n) + 4e-5; flag iff R~ + margin >= rowRunningMax
// (monotone LDS atomicMax, per 64-row x candSplit block; stale threshold
// only over-flags => safe). Exact path: F verbatim hs copy in LDS,
// sequential fmaf chain, u64 key tie-break -- byte-identical to r9-r24.
//
// Scratch in z_q float region of d_out (kZQ overwrites last); no d_ws.
// High-water 4,483,080 floats (= r14-r24's proven-safe envelope).

#define N_ROWS 16384
#define K_CAND 8192
#define CDIM   256
#define NELEM  4194304

#define SA_FLT   0          // A[16384] fp32 (numpy-pairwise-exact)
#define SK_FLT   16384      // keys u64[16384]
#define SL_FLT   49152      // lossAcc double
#define SQC_FLT  49160      // qcount u32[2048]
#define SBB_FLT  51208      // -B~ f32[8192]
#define SQ_FLT   59400      // queue u32[2048*624]
#define SFB_FLT  1337352    // fbf = bf16(2*f)[16384][256] as u16
#define SEB_FLT  3434504    // ebf2 = bf16(e) 16-cand panels (ends 4483080)
#define QCAP     624

typedef __attribute__((ext_vector_type(8))) short short8;
typedef __attribute__((ext_vector_type(4))) float f32x4;
typedef __attribute__((ext_vector_type(4))) unsigned uint32x4;

__device__ __forceinline__ unsigned short f2bf_rne(float x) {
    unsigned u = __float_as_uint(x);
    return (unsigned short)((u + 0x7fffu + ((u >> 16) & 1u)) >> 16);
}
__device__ __forceinline__ float bf2f(unsigned short u) {
    return __uint_as_float(((unsigned)u) << 16);
}
// monotone float->u32 map (handles negatives)
__device__ __forceinline__ unsigned ordU(float f) {
    unsigned u = __float_as_uint(f);
    return u ^ (((int)u >> 31) | 0x80000000u);
}

// ---- kAFE: fused kA + kFbf (blocks 0..511) ++ kEbf (blocks 512..543) -------
// kAF part: grid 512 = 16 b x 32 yB; 32 rows x 256 c per block.
// kEbf part: 32 blocks x 256 threads; panel layout g*4096 + kc*128 + cl*8.
__global__ __launch_bounds__(256) void kAFE(const float* __restrict__ hs,
                                            const float* __restrict__ emb,
                                            float* __restrict__ out) {
    const int t = threadIdx.x, blk = blockIdx.x;

    if (blk >= 512) {                     // ---- kEbf body (byte-identical)
        unsigned short* ebf = (unsigned short*)(out + SEB_FLT);
        float* bbfNeg = out + SBB_FLT;
        int cand = (blk - 512) * 256 + t;
        const float* ep = emb + ((size_t)cand << 8);
        unsigned short* dp = ebf + (((size_t)(cand >> 4)) << 12) + (cand & 15) * 8;
        float s = 0.f;
        for (int c0 = 0; c0 < 256; c0 += 8) {
            short8 v;
            #pragma unroll
            for (int j = 0; j < 8; ++j) {
                unsigned short bb = f2bf_rne(ep[c0 + j]);
                v[j] = (short)bb;
                float eh = bf2f(bb);
                s = fmaf(eh, eh, s);
            }
            *(short8*)(dp + (c0 >> 3) * 128) = v;
        }
        bbfNeg[cand] = -s;
        return;
    }

    // ---- kAF body (byte-identical to r22)
    float* A = out + SA_FLT;
    unsigned long long* keys = (unsigned long long*)(out + SK_FLT);
    unsigned short* fbf = (unsigned short*)(out + SFB_FLT);
    __shared__ float T[256][33];

    const int b = blk >> 5, yB = blk & 31;
    const int row0 = b * 1024 + yB * 32;
    if (blk == 0 && t == 0) *(double*)(out + SL_FLT) = 0.0;
    if (t < 32) keys[row0 + t] = ~0ull;

    // stage 32 rows x 256 c fp32 VERBATIM (coalesced per 32-lane group)
    {
        int yl = t & 31, ch = t >> 5;     // ch 0..7
        const float* src = hs + ((size_t)b << 18) + yB * 32 + yl;
        #pragma unroll
        for (int i = 0; i < 32; ++i) {
            int c = i * 8 + ch;
            T[c][yl] = src[(size_t)c << 10];
        }
    }
    __syncthreads();

    // A-chain: wave 0 only; lane = yl + h*32. Ops identical to old kA:
    // per-h r[8] stripes, pairwise combine, then fadd(hsum0, hsum1).
    if (t < 64) {
        int yl = t & 31, h = t >> 5;
        float r[8];
        #pragma unroll
        for (int j = 0; j < 8; ++j) {
            float x = T[h * 128 + j][yl];
            r[j] = __fmul_rn(x, x);
        }
        for (int i = 8; i < 128; i += 8) {
            #pragma unroll
            for (int j = 0; j < 8; ++j) {
                float x = T[h * 128 + i + j][yl];
                r[j] = __fadd_rn(r[j], __fmul_rn(x, x));
            }
        }
        float hsum = __fadd_rn(
            __fadd_rn(__fadd_rn(r[0], r[1]), __fadd_rn(r[2], r[3])),
            __fadd_rn(__fadd_rn(r[4], r[5]), __fadd_rn(r[6], r[7])));
        float other = __shfl_down(hsum, 32);   // h=1 partner's hsum
        if (h == 0) A[row0 + yl] = __fadd_rn(hsum, other);
    }

    // fbf transpose: all threads; thread (yl, cq) emits 32 c of its row
    {
        int yl = t & 31, cq = t >> 5;
        unsigned short* dst = fbf + (((size_t)(row0 + yl)) << 8) + cq * 32;
        #pragma unroll
        for (int v = 0; v < 4; ++v) {
            short8 w;
            #pragma unroll
            for (int j = 0; j < 8; ++j)
                w[j] = (short)f2bf_rne(2.0f * T[cq * 32 + v * 8 + j][yl]);
            *(short8*)(dst + v * 8) = w;
        }
    }
}

// ---- kScr: MFMA screen + flags -> per-half queues --------------------------
// grid 1024 = 256 rowBlk x 4 candSplit. acc[4][4] = 64 AGPR; cap 170.
// Fragment-linear A-tile with XOR swizzle D^=(c32&7) on BOTH sides.
// r25: cross-flag-phase prefetch of next cc's ks=0 B-frags (bf0[4]) --
// issued after the MFMA block, before the flag phase, so the may-alias
// queue stores pin them in place and the flag VALU hides the L2 latency.
__global__ __launch_bounds__(256, 3) void kScr(const float* __restrict__ hs,
                                               const float* __restrict__ emb,
                                               float* __restrict__ out) {
    const float* A = out + SA_FLT;
    unsigned* qcount = (unsigned*)(out + SQC_FLT);
    const float* bbfNeg = out + SBB_FLT;
    unsigned* queue = (unsigned*)(out + SQ_FLT);
    const unsigned short* fbf = (const unsigned short*)(out + SFB_FLT);
    const unsigned short* ebf = (const unsigned short*)(out + SEB_FLT);

    __shared__ __align__(16) short As2[16384];    // fragment-linear A-tile
    __shared__ unsigned rowMaxOrd[64];
    __shared__ float margLds[64];
    __shared__ int lqnH[2];

    const int t = threadIdx.x, blk = blockIdx.x;
    const int row0 = (blk >> 2) * 64;
    const int candSplit = (blk & 3) * 2048;
    const int lane = t & 63, wid = t >> 6;
    const int quad = lane >> 4, l15 = lane & 15;
    const int qb0 = (blk >> 2) * 8 + (blk & 3);
    unsigned* qB[2] = { queue + (size_t)qb0 * QCAP,
                        queue + (size_t)(qb0 + 4) * QCAP };

    if (t < 64) {
        rowMaxOrd[t] = 0u;
        margLds[t] = 2.0e-5f * sqrtf(A[row0 + t]) + 4.0e-5f;
    }
    if (t < 2) lqnH[t] = 0;

    // stage A-tile ONCE, swizzled fragment-linear:
    // canonical chunk D = (r>>4)*512 + c32*16 + (r&15); store at D^(c32&7).
    {
        const unsigned short* src = fbf + ((size_t)row0 << 8);
        #pragma unroll
        for (int i = 0; i < 8; ++i) {
            int d = i * 256 + t;
            short8 v = *(const short8*)(src + d * 8);
            int r = d >> 5, c32 = d & 31;
            int D = ((r >> 4) << 9) + (c32 << 4) + (r & 15);
            D ^= (c32 & 7);
            *(short8*)&As2[D << 3] = v;
        }
    }
    __syncthreads();     // the ONLY barrier before the final qcount store

    // read-side swizzled offsets (shorts): even ks -> off0, odd ks -> off1
    const int off0 = ((quad << 4) + (l15 ^ quad)) << 3;
    const int off1 = ((quad << 4) + (l15 ^ quad ^ 4)) << 3;

    // loop-invariant margins -> registers (one batched LDS read per m)
    f32x4 mgv[4];
    #pragma unroll
    for (int m = 0; m < 4; ++m)
        mgv[m] = *(const f32x4*)&margLds[m * 16 + quad * 4];

    // prologue: preload cc=0's ks=0 B-frags
    short8 bf0[4];
    {
        const unsigned short* e0 = ebf + (((size_t)(candSplit + wid * 64)) << 8)
                                       + quad * 128 + l15 * 8;
        #pragma unroll
        for (int jc = 0; jc < 4; ++jc)
            bf0[jc] = *(const short8*)(e0 + jc * 4096);
    }

    for (int cc = 0; cc < 8; ++cc) {
        const int candW = candSplit + cc * 256 + wid * 64;
        const unsigned short* ebW = ebf + (((size_t)candW) << 8)
                                       + quad * 128 + l15 * 8;
        float bneg[4];
        #pragma unroll
        for (int jc = 0; jc < 4; ++jc)
            bneg[jc] = bbfNeg[candW + jc * 16 + l15];

        f32x4 acc[4][4];
        #pragma unroll
        for (int jc = 0; jc < 4; ++jc)
            #pragma unroll
            for (int m = 0; m < 4; ++m)
                acc[m][jc] = (f32x4){0.f, 0.f, 0.f, 0.f};

        // ks = 0: consume the prefetched bf0 (same bytes/order as before)
        #pragma unroll
        for (int m = 0; m < 4; ++m) {
            short8 af = *(const short8*)&As2[((m * 8 + 0) << 9) + off0];
            #pragma unroll
            for (int jc = 0; jc < 4; ++jc)
                acc[m][jc] = __builtin_amdgcn_mfma_f32_16x16x32_bf16(
                    af, bf0[jc], acc[m][jc], 0, 0, 0);
        }
        // ks = 1..7: in-loop loads (fully unrolled; compiler schedules)
        #pragma unroll
        for (int ks = 1; ks < 8; ++ks) {
            short8 bf[4];
            #pragma unroll
            for (int jc = 0; jc < 4; ++jc)
                bf[jc] = *(const short8*)(ebW + jc * 4096 + ks * 512);
            #pragma unroll
            for (int m = 0; m < 4; ++m) {
                short8 af = *(const short8*)&As2[((m * 8 + ks) << 9)
                                                 + ((ks & 1) ? off1 : off0)];
                #pragma unroll
                for (int jc = 0; jc < 4; ++jc)
                    acc[m][jc] = __builtin_amdgcn_mfma_f32_16x16x32_bf16(
                        af, bf[jc], acc[m][jc], 0, 0, 0);
            }
        }

        // prefetch NEXT cc's ks=0 frags BEFORE the flag phase: the queue
        // stores below may-alias ebf (both in out), so these loads cannot
        // be reordered past them -- their L2 latency hides under the flag
        // VALU instead of stalling the next cc's first MFMAs.
        {
            const int ccn = (cc < 7) ? cc + 1 : 7;   // cc=7: in-bounds dummy
            const unsigned short* ebWn = ebf
                + (((size_t)(candSplit + ccn * 256 + wid * 64)) << 8)
                + quad * 128 + l15 * 8;
            #pragma unroll
            for (int jc = 0; jc < 4; ++jc)
                bf0[jc] = *(const short8*)(ebWn + jc * 4096);
        }

        // flag: per-(m,reg) early-out; ballot consensus so the 16-lane
        // shuffle-max never runs with inactive lanes (garbage-max hazard).
        #pragma unroll
        for (int m = 0; m < 4; ++m) {
            uint32x4 thv = *(const uint32x4*)&rowMaxOrd[m * 16 + quad * 4];
            #pragma unroll
            for (int reg = 0; reg < 4; ++reg) {
                int rl = m * 16 + quad * 4 + reg;
                float x0 = __fadd_rn(acc[m][0][reg], bneg[0]);
                float x1 = __fadd_rn(acc[m][1][reg], bneg[1]);
                float x2 = __fadd_rn(acc[m][2][reg], bneg[2]);
                float x3 = __fadd_rn(acc[m][3][reg], bneg[3]);
                float vmax = fmaxf(fmaxf(x0, x1), fmaxf(x2, x3));
                unsigned th = thv[reg];
                float mg = mgv[m][reg];
                bool hot = ordU(__fadd_rn(vmax, mg)) >= th;
                unsigned long long bal = __ballot(hot);
                if (((bal >> (quad * 16)) & 0xFFFFull) == 0ull) continue;
                float g = vmax;                       // all 16 lanes active
                g = fmaxf(g, __shfl_xor(g, 1, 16));
                g = fmaxf(g, __shfl_xor(g, 2, 16));
                g = fmaxf(g, __shfl_xor(g, 4, 16));
                g = fmaxf(g, __shfl_xor(g, 8, 16));
                unsigned og = ordU(g);
                if (og > th) { atomicMax(&rowMaxOrd[rl], og); th = og; }
                float xs[4] = {x0, x1, x2, x3};
                #pragma unroll
                for (int jc = 0; jc < 4; ++jc) {
                    if (ordU(__fadd_rn(xs[jc], mg)) >= th) {
                        int slot = atomicAdd(&lqnH[m >> 1], 1);
                        if (slot < QCAP)
                            qB[m >> 1][slot] = ((unsigned)(rl & 31) << 13)
                                             | (unsigned)(candW + jc * 16 + l15);
                    }
                }
            }
        }
    }
    __syncthreads();
    if (t < 2) qcount[qb0 + t * 4] = (unsigned)lqnH[t];
}

// ---- kTailM: merged tail -- stage F once, drain 4 candSplit queues ---------
// grid 512 (one block per 32-row group). Queues at R*4+s. Exact chain
// byte-identical to r9-r24.
__global__ __launch_bounds__(256, 4) void kTailM(const float* __restrict__ hs,
                                                 const float* __restrict__ emb,
                                                 float* __restrict__ out) {
    const float* A = out + SA_FLT;
    unsigned long long* keys = (unsigned long long*)(out + SK_FLT);
    const unsigned* qcount = (const unsigned*)(out + SQC_FLT);
    const unsigned* queue = (const unsigned*)(out + SQ_FLT);

    __shared__ __align__(16) float F[32][264];

    const int t = threadIdx.x, R = blockIdx.x;
    const int row0 = R * 32;

    int nq[4];
    #pragma unroll
    for (int s = 0; s < 4; ++s) nq[s] = (int)qcount[R * 4 + s];
    if ((nq[0] | nq[1] | nq[2] | nq[3]) == 0) return;

    // stage 32 rows fp32 VERBATIM into LDS (once, not 4x)
    {
        int yl = t & 31, cq = t >> 5;
        int nrow = row0 + yl;
        int b = nrow >> 10, yx = nrow & 1023;
        const float* src = hs + ((size_t)b << 18) + yx;
        #pragma unroll
        for (int i = 0; i < 32; ++i) {
            int c = i * 8 + cq;
            F[yl][c] = src[(size_t)c << 10];
        }
    }
    __syncthreads();

    for (int s = 0; s < 4; ++s) {
        int n = nq[s];
        if (n == 0) continue;
        if (n > QCAP) {                   // overflow: full scan of split s
            int cb = s * 2048;
            for (int p = t; p < 32 * 2048; p += 256) {
                int rl = p >> 11, cand = cb + (p & 2047);
                const float* ep = emb + ((size_t)cand << 8);
                float acc = 0.f;
                #pragma unroll 8
                for (int c0 = 0; c0 < 256; c0 += 4) {
                    f32x4 f4 = *(const f32x4*)&F[rl][c0];
                    f32x4 e4 = *(const f32x4*)(ep + c0);
                    acc = fmaf(f4[0], e4[0], acc);
                    acc = fmaf(f4[1], e4[1], acc);
                    acc = fmaf(f4[2], e4[2], acc);
                    acc = fmaf(f4[3], e4[3], acc);
                }
                int row = row0 + rl;
                float d = __fsub_rn(A[row], __fadd_rn(acc, acc));
                unsigned long long key =
                    ((unsigned long long)__float_as_uint(d) << 32) | (unsigned)cand;
                atomicMin(&keys[row], key);
            }
            continue;
        }
        const unsigned* qBlk = queue + (size_t)(R * 4 + s) * QCAP;
        for (int i = t; i < n; i += 256) {
            unsigned e = qBlk[i];
            int rl = (int)(e >> 13), cand = (int)(e & 8191u);
            const float* ep = emb + ((size_t)cand << 8);
            float acc = 0.f;
            #pragma unroll 8
            for (int c0 = 0; c0 < 256; c0 += 4) {
                f32x4 f4 = *(const f32x4*)&F[rl][c0];     // LDS, exact hs copy
                f32x4 e4 = *(const f32x4*)(ep + c0);      // global fp32 emb
                acc = fmaf(f4[0], e4[0], acc);
                acc = fmaf(f4[1], e4[1], acc);
                acc = fmaf(f4[2], e4[2], acc);
                acc = fmaf(f4[3], e4[3], acc);
            }
            int row = row0 + rl;
            float d = __fsub_rn(A[row], __fadd_rn(acc, acc));
            unsigned long long key =
                ((unsigned long long)__float_as_uint(d) << 32) | (unsigned)cand;
            atomicMin(&keys[row], key);
        }
    }
}

// ---- kPost: keys -> indices + loss partials (BEFORE any z_q write) ---------
__global__ void kPost(float* __restrict__ out) {
    const unsigned long long* keys = (const unsigned long long*)(out + SK_FLT);
    double* lossAcc = (double*)(out + SL_FLT);
    __shared__ double sd[256];
    int n = blockIdx.x * 256 + threadIdx.x;
    unsigned long long key = keys[n];
    unsigned idx = (unsigned)(key & 0xffffffffu) & 8191u;
    float d = __uint_as_float((unsigned)(key >> 32));
    out[NELEM + n] = (float)idx;
    sd[threadIdx.x] = (double)d;
    __syncthreads();
    for (int s = 128; s > 0; s >>= 1) {
        if (threadIdx.x < s) sd[threadIdx.x] += sd[threadIdx.x + s];
        __syncthreads();
    }
    if (threadIdx.x == 0) atomicAdd(lossAcc, sd[0]);
}

__global__ void kLoss(float* __restrict__ out) {
    if (threadIdx.x == 0) {
        double loss = 1.25 * (*(const double*)(out + SL_FLT)) / (double)NELEM;
        out[NELEM + N_ROWS] = (float)loss;
    }
}

// ---- kZQ: 64n x 64c LDS-tiled gather (reads indices from output region) ----
// grid 1024 = 256 nTile x 4 cTile. idx from out[NELEM+n] (stable, outside
// z_q region). Per-element formula byte-identical: out = fadd(h, fsub(e,h)).
__global__ __launch_bounds__(256) void kZQ(const float* __restrict__ hs,
                                           const float* __restrict__ emb,
                                           float* __restrict__ out) {
    __shared__ float E[64][65];           // [local c][local n]
    __shared__ unsigned idxL[64];

    const int t = threadIdx.x, blk = blockIdx.x;
    const int nt = blk >> 2, ct = blk & 3;
    const int row0 = nt * 64, c0 = ct * 64;
    const int b = row0 >> 10, yx0 = row0 & 1023;

    if (t < 64) idxL[t] = (unsigned)out[NELEM + row0 + t] & 8191u;
    __syncthreads();

    // gather: 4 threads/row, each reads 16 consecutive c (64B) -> LDS scatter
    {
        int r = t >> 2, j = t & 3;
        const float* ep = emb + ((size_t)idxL[r] << 8) + c0 + j * 16;
        #pragma unroll
        for (int q = 0; q < 4; ++q) {
            f32x4 v = *(const f32x4*)(ep + q * 4);
            #pragma unroll
            for (int i = 0; i < 4; ++i)
                E[j * 16 + q * 4 + i][r] = v[i];
        }
    }
    __syncthreads();

    // emit: thread (yl, ch): 16 c each; h read / z_q write coalesced
    {
        int yl = t & 63, ch = t >> 6;
        #pragma unroll
        for (int i = 0; i < 16; ++i) {
            int cl = ch * 16 + i;
            size_t o = ((size_t)b << 18) | ((size_t)(c0 + cl) << 10)
                     | (size_t)(yx0 + yl);
            float h = hs[o];
            float e = E[cl][yl];
            out[o] = __fadd_rn(h, __fsub_rn(e, h));
        }
    }
}

extern "C" void kernel_launch(void* const* d_in, const int* in_sizes, int n_in,
                              void* d_out, int out_size, void* d_ws, size_t ws_size,
                              hipStream_t stream) {
    const float* hs  = (const float*)d_in[0];
    const float* emb = (const float*)d_in[1];
    float* out = (float*)d_out;

    kAFE<<<544, 256, 0, stream>>>(hs, emb, out);
    kScr<<<1024, 256, 0, stream>>>(hs, emb, out);
    kTailM<<<512, 256, 0, stream>>>(hs, emb, out);
    kPost<<<N_ROWS / 256, 256, 0, stream>>>(out);
    kLoss<<<1, 64, 0, stream>>>(out);
    kZQ<<<1024, 256, 0, stream>>>(hs, emb, out);
}